// Round 18
// baseline (372.704 us; speedup 1.0000x reference)
//
#include <hip/hip_runtime.h>
#include <hip/hip_bf16.h>
#include <string.h>

#define EPSBN 1e-3f

constexpr int kC1  = 192;
constexpr int kN2  = 240;
constexpr int kOut = 121;
constexpr int BTOT = 16384;

typedef __attribute__((ext_vector_type(8))) short bf16x8;
typedef __attribute__((ext_vector_type(4))) float f32x4;

__device__ __forceinline__ unsigned short f2bf(float f) {
  union { float f; unsigned u; } v; v.f = f;
  unsigned r = v.u + 0x7FFFu + ((v.u >> 16) & 1u);
  return (unsigned short)(r >> 16);
}
__device__ __forceinline__ float bf2f(unsigned short h) {
  union { unsigned u; float f; } v; v.u = ((unsigned)h) << 16;
  return v.f;
}

// ---------------- d_ws layout (bytes) ----------------
constexpr size_t OFF_W1E  = 0;
constexpr size_t OFF_W2E  = OFF_W1E + 73728;
constexpr size_t OFF_W3E  = OFF_W2E + 92160;
constexpr size_t OFF_W1B  = OFF_W3E + 65536;
constexpr size_t OFF_W2B  = OFF_W1B + 24576;
constexpr size_t OFF_BIAS = OFF_W2B + 4096;
constexpr size_t OFF_CWT  = OFF_BIAS + 2736;
constexpr size_t WS_NEED  = OFF_CWT + 122880;

// ======================= prep: conv_w transpose =======================
__global__ __launch_bounds__(256) void prep_cwt(const float* __restrict__ cw,
                                                float* __restrict__ cwt4)
{
  int idx = blockIdx.x * 256 + threadIdx.x;
  if (idx < 7680) {
    int f = idx >> 6, w = idx & 63;
    float4 v;
    v.x = cw[(size_t)w * 360 + f * 3 + 0];
    v.y = cw[(size_t)w * 360 + f * 3 + 1];
    v.z = cw[(size_t)w * 360 + f * 3 + 2];
    v.w = 0.f;
    *reinterpret_cast<float4*>(cwt4 + (size_t)idx * 4) = v;
  }
}

// ======================= prep: pack weights into MFMA B-fragment order =======================
__device__ __forceinline__ void pack_one(unsigned short* dst, int idx,
                                         const float* __restrict__ W, int Ksrc, int Nsrc,
                                         int KS, const float* g, const float* v)
{
  int per_nt = KS * 512;
  int nt = idx / per_nt; int r = idx - nt * per_nt;
  int ks = r >> 9; int r2 = r & 511;
  int l = r2 >> 3; int j = r2 & 7;
  int i = ks * 32 + ((l >> 4) << 3) + j;
  int n = (nt << 4) + (l & 15);
  float val = 0.f;
  if (i < Ksrc && n < Nsrc) {
    float s = g ? g[i] * rsqrtf(v[i] + EPSBN) : 1.f;
    val = s * W[(size_t)i * Nsrc + n];
  }
  dst[idx] = f2bf(val);
}

__global__ __launch_bounds__(256) void prep_pack(
    const float* e_g1, const float* e_v1, const float* e_d1_w,
    const float* e_g2, const float* e_v2, const float* e_d2_w,
    const float* e_d3_w,
    const float* b_g1, const float* b_v1, const float* b_d1_w,
    const float* b_g2, const float* b_v2, const float* b_d2_w,
    unsigned short* W1E, unsigned short* W2E, unsigned short* W3E,
    unsigned short* W1B, unsigned short* W2B)
{
  int e = blockIdx.x * 256 + threadIdx.x;
  if (e < 36864)                       pack_one(W1E, e,          e_d1_w, 192, 192, 6, e_g1, e_v1);
  else if (e < 36864 + 46080)          pack_one(W2E, e - 36864,  e_d2_w, 192, 240, 6, e_g2, e_v2);
  else if (e < 82944 + 32768)          pack_one(W3E, e - 82944,  e_d3_w, 240, 120, 8, nullptr, nullptr);
  else if (e < 115712 + 12288)         pack_one(W1B, e - 115712, b_d1_w, 192, 64,  6, b_g1, b_v1);
  else if (e < 128000 + 2048)          pack_one(W2B, e - 128000, b_d2_w, 64,  32,  2, b_g2, b_v2);
}

// ======================= prep: folded biases =======================
__global__ __launch_bounds__(256) void prep_bias(
    const float* e_g1, const float* e_b1, const float* e_m1, const float* e_v1,
    const float* e_d1_w, const float* e_d1_b,
    const float* e_g2, const float* e_b2, const float* e_m2, const float* e_v2,
    const float* e_d2_w, const float* e_d2_b, const float* e_d3_b,
    const float* b_g1, const float* b_b1, const float* b_m1, const float* b_v1,
    const float* b_d1_w, const float* b_d1_b,
    const float* b_g2, const float* b_b2, const float* b_m2, const float* b_v2,
    const float* b_d2_w, const float* b_d2_b,
    const float* b_d3_w, const float* b_d3_b,
    float* BIAS)
{
  int q = blockIdx.x * 256 + threadIdx.x;
  if (q < 192) {
    int j = q; float acc = e_d1_b[j];
    for (int i = 0; i < 192; ++i) {
      float s = e_g1[i] * rsqrtf(e_v1[i] + EPSBN);
      acc += (e_b1[i] - e_m1[i] * s) * e_d1_w[(size_t)i * 192 + j];
    }
    BIAS[q] = acc;
  } else if (q < 432) {
    int j = q - 192; float acc = e_d2_b[j];
    for (int i = 0; i < 192; ++i) {
      float s = e_g2[i] * rsqrtf(e_v2[i] + EPSBN);
      acc += (e_b2[i] - e_m2[i] * s) * e_d2_w[(size_t)i * 240 + j];
    }
    BIAS[q] = acc;
  } else if (q < 552) {
    BIAS[q] = e_d3_b[q - 432];
  } else if (q < 616) {
    int j = q - 552; float acc = b_d1_b[j];
    for (int i = 0; i < 192; ++i) {
      float s = b_g1[i] * rsqrtf(b_v1[i] + EPSBN);
      acc += (b_b1[i] - b_m1[i] * s) * b_d1_w[(size_t)i * 64 + j];
    }
    BIAS[q] = acc;
  } else if (q < 648) {
    int j = q - 616; float acc = b_d2_b[j];
    for (int i = 0; i < 64; ++i) {
      float s = b_g2[i] * rsqrtf(b_v2[i] + EPSBN);
      acc += (b_b2[i] - b_m2[i] * s) * b_d2_w[(size_t)i * 32 + j];
    }
    BIAS[q] = acc;
  } else if (q < 680) {
    BIAS[q] = b_d3_w[q - 648];
  } else if (q == 680) {
    BIAS[q] = b_d3_b[0];
  }
}

// ======================= FUSED v5: R14 + register double-buffered x staging =======================
// 1 wave = 16 rows, grid 1024 (R14 structure, best known = 187us). Change:
// conv stage loop prefetches the NEXT half-row's 15 f4 into registers before
// computing the current one -> ~900cyc HBM latency hides under ~2Kcyc compute.
// Accumulation order unchanged (h=0 then h=1, f ascending) -> bitwise-same.
__global__ __launch_bounds__(64) void fused_all(
    const float* __restrict__ x,
    const float* __restrict__ cwt4, const float* __restrict__ conv_b,
    const unsigned short* __restrict__ W1E, const unsigned short* __restrict__ W2E,
    const unsigned short* __restrict__ W3E, const unsigned short* __restrict__ W1B,
    const unsigned short* __restrict__ W2B, const float* __restrict__ BIAS,
    float* __restrict__ out)
{
  __shared__ __align__(16) short Ac[16 * 200];     // 6.4 KB
  __shared__ __align__(16) char  ubuf[15 * 65 * 16]; // conv xt; mlp Hs/H2 alias

  float4* xt = reinterpret_cast<float4*>(ubuf);          // [15][65] f4, conv phase
  short*  Hs = reinterpret_cast<short*>(ubuf);           // [16][200], mlp phase
  short*  H2 = reinterpret_cast<short*>(ubuf + 6400);    // [16][264], mlp phase

  const int l = threadIdx.x;       // conv: = w ; mlp: lane
  const int R = blockIdx.x * 16;

  // ================= conv phase (double-buffered stages) =================
  {
    const float bc0 = conv_b[l * 3 + 0];
    const float bc1 = conv_b[l * 3 + 1];
    const float bc2 = conv_b[l * 3 + 2];

    // per-lane stage mapping (same every stage): g = i*64+l -> (w, fs)
    int wi[15], fsi[15];
    #pragma unroll
    for (int i = 0; i < 15; ++i) {
      int g = i * 64 + l;
      wi[i] = g / 15; fsi[i] = g - 15 * wi[i];
    }

    float4 v[15];
    // prologue: stage (r=0, h=0)
    {
      const float* xrow = x + (size_t)R * 7680;
      #pragma unroll
      for (int i = 0; i < 15; ++i)
        v[i] = *reinterpret_cast<const float4*>(xrow + wi[i] * 120 + 4 * fsi[i]);
    }

    float a0 = 0.f, a1 = 0.f, a2 = 0.f;
    for (int st = 0; st < 32; ++st) {     // stage = r*2 + h
      const int r = st >> 1, h = st & 1;

      // write current stage regs -> xt
      #pragma unroll
      for (int i = 0; i < 15; ++i)
        xt[fsi[i] * 65 + wi[i]] = v[i];
      __syncthreads();   // 1-wave: waitcnt only

      // issue next stage's loads (overlap HBM latency with compute below)
      if (st < 31) {
        const int ns = st + 1, nr = ns >> 1, nh = ns & 1;
        const float* xrow = x + (size_t)(R + nr) * 7680;
        #pragma unroll
        for (int i = 0; i < 15; ++i)
          v[i] = *reinterpret_cast<const float4*>(xrow + wi[i] * 120 + nh * 60 + 4 * fsi[i]);
      }

      // compute current stage (lane owns w = l)
      if (h == 0) { a0 = 0.f; a1 = 0.f; a2 = 0.f; }
      #pragma unroll 5
      for (int fq = 0; fq < 15; ++fq) {
        float4 x4 = xt[fq * 65 + l];
        float xs[4] = {x4.x, x4.y, x4.z, x4.w};
        #pragma unroll
        for (int j = 0; j < 4; ++j) {
          int f = h * 60 + 4 * fq + j;
          float4 c4 = *reinterpret_cast<const float4*>(cwt4 + (size_t)(f * 64 + l) * 4);
          a0 = fmaf(xs[j], c4.x, a0);
          a1 = fmaf(xs[j], c4.y, a1);
          a2 = fmaf(xs[j], c4.z, a2);
        }
      }
      if (h == 1) {
        Ac[r * 200 + 3 * l + 0] = (short)f2bf(tanhf(a0 + bc0));
        Ac[r * 200 + 3 * l + 1] = (short)f2bf(tanhf(a1 + bc1));
        Ac[r * 200 + 3 * l + 2] = (short)f2bf(tanhf(a2 + bc2));
      }
      __syncthreads();   // xt reads done before next stage's writes
    }
  }
  __syncthreads();   // conv done; ubuf switches role to Hs/H2

  // ---- zero H2 k-pad [240,256): stale aliased bytes can be bf16 NaN; NaN*0=NaN in MFMA ----
  #pragma unroll
  for (int e = l; e < 256; e += 64) {
    int row = e >> 4, cc = e & 15;
    H2[row * 264 + 240 + cc] = 0;
  }

  const int arow = l & 15;
  const int kofs = (l >> 4) * 8;
  const int mb   = (l >> 4) * 4;

  // ---- d1e: [192->192], tanh -> Hs ----
  for (int nt = 0; nt < 12; ++nt) {
    f32x4 acc = {0.f, 0.f, 0.f, 0.f};
    const bf16x8* bp = (const bf16x8*)W1E + (size_t)(nt * 6) * 64 + l;
    #pragma unroll
    for (int ks = 0; ks < 6; ++ks) {
      bf16x8 a = *(const bf16x8*)(Ac + arow * 200 + ks * 32 + kofs);
      acc = __builtin_amdgcn_mfma_f32_16x16x32_bf16(a, bp[(size_t)ks * 64], acc, 0, 0, 0);
    }
    int n = nt * 16 + arow;
    float bv = BIAS[n];
    __syncthreads();
    #pragma unroll
    for (int r = 0; r < 4; ++r)
      Hs[(mb + r) * 200 + n] = (short)f2bf(tanhf(acc[r] + bv));
  }
  __syncthreads();

  // ---- d2e: [192->240] -> H2 ----
  for (int nt = 0; nt < 15; ++nt) {
    f32x4 acc = {0.f, 0.f, 0.f, 0.f};
    const bf16x8* bp = (const bf16x8*)W2E + (size_t)(nt * 6) * 64 + l;
    #pragma unroll
    for (int ks = 0; ks < 6; ++ks) {
      bf16x8 a = *(const bf16x8*)(Hs + arow * 200 + ks * 32 + kofs);
      acc = __builtin_amdgcn_mfma_f32_16x16x32_bf16(a, bp[(size_t)ks * 64], acc, 0, 0, 0);
    }
    int n = nt * 16 + arow;
    float bv = BIAS[192 + n];
    #pragma unroll
    for (int r = 0; r < 4; ++r)
      H2[(mb + r) * 264 + n] = (short)f2bf(acc[r] + bv);
  }
  __syncthreads();

  // ---- d3e: [240(pad256)->120] -> out ----
  for (int nt = 0; nt < 8; ++nt) {
    f32x4 acc = {0.f, 0.f, 0.f, 0.f};
    const bf16x8* bp = (const bf16x8*)W3E + (size_t)(nt * 8) * 64 + l;
    #pragma unroll
    for (int ks = 0; ks < 8; ++ks) {
      bf16x8 a = *(const bf16x8*)(H2 + arow * 264 + ks * 32 + kofs);
      acc = __builtin_amdgcn_mfma_f32_16x16x32_bf16(a, bp[(size_t)ks * 64], acc, 0, 0, 0);
    }
    int n = nt * 16 + arow;
    if (n < 120) {
      float bv = BIAS[432 + n];
      #pragma unroll
      for (int r = 0; r < 4; ++r)
        out[(size_t)(R + mb + r) * kOut + n] = acc[r] + bv;
    }
  }
  __syncthreads();

  // ---- g1 blink: [192->64], tanh -> Hs ----
  for (int nt = 0; nt < 4; ++nt) {
    f32x4 acc = {0.f, 0.f, 0.f, 0.f};
    const bf16x8* bp = (const bf16x8*)W1B + (size_t)(nt * 6) * 64 + l;
    #pragma unroll
    for (int ks = 0; ks < 6; ++ks) {
      bf16x8 a = *(const bf16x8*)(Ac + arow * 200 + ks * 32 + kofs);
      acc = __builtin_amdgcn_mfma_f32_16x16x32_bf16(a, bp[(size_t)ks * 64], acc, 0, 0, 0);
    }
    int n = nt * 16 + arow;
    float bv = BIAS[552 + n];
    #pragma unroll
    for (int r = 0; r < 4; ++r)
      Hs[(mb + r) * 200 + n] = (short)f2bf(tanhf(acc[r] + bv));
  }
  __syncthreads();

  // ---- g2 blink: [64->32], tanh -> H2 ----
  for (int nt = 0; nt < 2; ++nt) {
    f32x4 acc = {0.f, 0.f, 0.f, 0.f};
    const bf16x8* bp = (const bf16x8*)W2B + (size_t)(nt * 2) * 64 + l;
    #pragma unroll
    for (int ks = 0; ks < 2; ++ks) {
      bf16x8 a = *(const bf16x8*)(Hs + arow * 200 + ks * 32 + kofs);
      acc = __builtin_amdgcn_mfma_f32_16x16x32_bf16(a, bp[(size_t)ks * 64], acc, 0, 0, 0);
    }
    int n = nt * 16 + arow;
    float bv = BIAS[616 + n];
    #pragma unroll
    for (int r = 0; r < 4; ++r)
      H2[(mb + r) * 264 + n] = (short)f2bf(tanhf(acc[r] + bv));
  }
  __syncthreads();

  // ---- out_b: [32->1], sigmoid ----
  if (l < 16) {
    float s = BIAS[680];
    #pragma unroll
    for (int i = 0; i < 32; ++i)
      s = fmaf(bf2f((unsigned short)H2[l * 264 + i]), BIAS[648 + i], s);
    out[(size_t)(R + l) * kOut + 120] = 1.f / (1.f + expf(-s));
  }
}

// ======================= Fallback: round-5 fused kernel (known-correct, fp32) =======================
constexpr int CSTR = 193;
__global__ __launch_bounds__(64, 4) void fused_blink_fb(
    const float* __restrict__ x,
    const float* __restrict__ conv_w, const float* __restrict__ conv_b,
    const float* __restrict__ e_g1, const float* __restrict__ e_b1,
    const float* __restrict__ e_m1, const float* __restrict__ e_v1,
    const float* __restrict__ e_d1_w, const float* __restrict__ e_d1_b,
    const float* __restrict__ e_g2, const float* __restrict__ e_b2,
    const float* __restrict__ e_m2, const float* __restrict__ e_v2,
    const float* __restrict__ e_d2_w, const float* __restrict__ e_d2_b,
    const float* __restrict__ e_d3_w, const float* __restrict__ e_d3_b,
    const float* __restrict__ b_g1, const float* __restrict__ b_b1,
    const float* __restrict__ b_m1, const float* __restrict__ b_v1,
    const float* __restrict__ b_d1_w, const float* __restrict__ b_d1_b,
    const float* __restrict__ b_g2, const float* __restrict__ b_b2,
    const float* __restrict__ b_m2, const float* __restrict__ b_v2,
    const float* __restrict__ b_d2_w, const float* __restrict__ b_d2_b,
    const float* __restrict__ b_d3_w, const float* __restrict__ b_d3_b,
    float* __restrict__ out)
{
  __shared__ float comb[4 * CSTR];
  __shared__ __align__(16) float Ab[4 * kN2];
  __shared__ __align__(16) float Bb[4 * kN2];
  const int lane = threadIdx.x;
  const int b0   = blockIdx.x * 4;
  {
    const int rcv = lane >> 4, wloc = lane & 15;
    for (int wc = 0; wc < 4; ++wc) {
      const int w = wc * 16 + wloc;
      const float* xr  = x + ((size_t)(b0 + rcv) * 64 + w) * 120;
      const float* cwp = conv_w + (size_t)w * 360;
      float a0 = 0.f, a1 = 0.f, a2 = 0.f;
      for (int t = 0; t < 30; ++t) {
        float4 xv = *reinterpret_cast<const float4*>(xr + 4 * t);
        float4 c0 = *reinterpret_cast<const float4*>(cwp + 12 * t);
        float4 c1 = *reinterpret_cast<const float4*>(cwp + 12 * t + 4);
        float4 c2 = *reinterpret_cast<const float4*>(cwp + 12 * t + 8);
        a0 += xv.x * c0.x + xv.y * c0.w + xv.z * c1.z + xv.w * c2.y;
        a1 += xv.x * c0.y + xv.y * c1.x + xv.z * c1.w + xv.w * c2.z;
        a2 += xv.x * c0.z + xv.y * c1.y + xv.z * c2.x + xv.w * c2.w;
      }
      comb[rcv * CSTR + 3 * w + 0] = tanhf(a0 + conv_b[3 * w + 0]);
      comb[rcv * CSTR + 3 * w + 1] = tanhf(a1 + conv_b[3 * w + 1]);
      comb[rcv * CSTR + 3 * w + 2] = tanhf(a2 + conv_b[3 * w + 2]);
    }
  }
  __syncthreads();
  #define AR(rr) (Ab + (size_t)(rr) * kN2)
  #define BR(rr) (Bb + (size_t)(rr) * kN2)
  #pragma unroll
  for (int q = 0; q < 12; ++q) {
    int rr = q / 3, cc = q % 3;
    int i = cc * 64 + lane;
    float s = e_g1[i] * rsqrtf(e_v1[i] + EPSBN);
    AR(rr)[i] = comb[rr * CSTR + i] * s + (e_b1[i] - e_m1[i] * s);
  }
  __syncthreads();
  {
    float acc[4][3];
    #pragma unroll
    for (int rr = 0; rr < 4; ++rr) { acc[rr][0]=acc[rr][1]=acc[rr][2]=0.f; }
    for (int i = 0; i < kC1; i += 4) {
      float4 v[4];
      #pragma unroll
      for (int rr = 0; rr < 4; ++rr) v[rr] = *reinterpret_cast<const float4*>(AR(rr) + i);
      #pragma unroll
      for (int io = 0; io < 4; ++io) {
        const float* wp = e_d1_w + (size_t)(i + io) * kC1 + lane;
        float w0 = wp[0], w1 = wp[64], w2 = wp[128];
        #pragma unroll
        for (int rr = 0; rr < 4; ++rr) {
          float xv = reinterpret_cast<const float*>(&v[rr])[io];
          acc[rr][0] = fmaf(xv, w0, acc[rr][0]);
          acc[rr][1] = fmaf(xv, w1, acc[rr][1]);
          acc[rr][2] = fmaf(xv, w2, acc[rr][2]);
        }
      }
    }
    #pragma unroll
    for (int c = 0; c < 3; ++c) {
      int j = c * 64 + lane;
      float s  = e_g2[j] * rsqrtf(e_v2[j] + EPSBN);
      float t  = e_b2[j] - e_m2[j] * s;
      float bs = e_d1_b[j];
      #pragma unroll
      for (int rr = 0; rr < 4; ++rr)
        BR(rr)[j] = tanhf(acc[rr][c] + bs) * s + t;
    }
  }
  __syncthreads();
  {
    const bool m3 = (lane < 48);
    float acc[4][4];
    #pragma unroll
    for (int rr = 0; rr < 4; ++rr) { acc[rr][0]=acc[rr][1]=acc[rr][2]=acc[rr][3]=0.f; }
    for (int i = 0; i < kC1; i += 4) {
      float4 v[4];
      #pragma unroll
      for (int rr = 0; rr < 4; ++rr) v[rr] = *reinterpret_cast<const float4*>(BR(rr) + i);
      #pragma unroll
      for (int io = 0; io < 4; ++io) {
        const float* wp = e_d2_w + (size_t)(i + io) * kN2 + lane;
        float w0 = wp[0], w1 = wp[64], w2 = wp[128];
        float w3 = m3 ? wp[192] : 0.f;
        #pragma unroll
        for (int rr = 0; rr < 4; ++rr) {
          float xv = reinterpret_cast<const float*>(&v[rr])[io];
          acc[rr][0] = fmaf(xv, w0, acc[rr][0]);
          acc[rr][1] = fmaf(xv, w1, acc[rr][1]);
          acc[rr][2] = fmaf(xv, w2, acc[rr][2]);
          acc[rr][3] = fmaf(xv, w3, acc[rr][3]);
        }
      }
    }
    #pragma unroll
    for (int c = 0; c < 4; ++c) {
      int j = c * 64 + lane;
      if (c < 3 || m3) {
        float bs = e_d2_b[j];
        #pragma unroll
        for (int rr = 0; rr < 4; ++rr)
          AR(rr)[j] = acc[rr][c] + bs;
      }
    }
  }
  __syncthreads();
  #pragma unroll
  for (int q = 0; q < 12; ++q) {
    int rr = q / 3, cc = q % 3;
    int i = cc * 64 + lane;
    float s = b_g1[i] * rsqrtf(b_v1[i] + EPSBN);
    BR(rr)[i] = comb[rr * CSTR + i] * s + (b_b1[i] - b_m1[i] * s);
  }
  {
    const bool m56 = (lane < 56);
    float acc[4][2];
    #pragma unroll
    for (int rr = 0; rr < 4; ++rr) { acc[rr][0]=acc[rr][1]=0.f; }
    for (int i = 0; i < kN2; i += 4) {
      float4 v[4];
      #pragma unroll
      for (int rr = 0; rr < 4; ++rr) v[rr] = *reinterpret_cast<const float4*>(AR(rr) + i);
      #pragma unroll
      for (int io = 0; io < 4; ++io) {
        const float* wp = e_d3_w + (size_t)(i + io) * 120 + lane;
        float w0 = wp[0];
        float w1 = m56 ? wp[64] : 0.f;
        #pragma unroll
        for (int rr = 0; rr < 4; ++rr) {
          float xv = reinterpret_cast<const float*>(&v[rr])[io];
          acc[rr][0] = fmaf(xv, w0, acc[rr][0]);
          acc[rr][1] = fmaf(xv, w1, acc[rr][1]);
        }
      }
    }
    #pragma unroll
    for (int c = 0; c < 2; ++c) {
      int j = c * 64 + lane;
      if (j < 120) {
        float bs = e_d3_b[j];
        #pragma unroll
        for (int rr = 0; rr < 4; ++rr)
          out[(size_t)(b0 + rr) * kOut + j] = acc[rr][c] + bs;
      }
    }
  }
  __syncthreads();
  {
    float acc[4] = {0.f, 0.f, 0.f, 0.f};
    for (int i = 0; i < kC1; i += 4) {
      float4 v[4];
      #pragma unroll
      for (int rr = 0; rr < 4; ++rr) v[rr] = *reinterpret_cast<const float4*>(BR(rr) + i);
      #pragma unroll
      for (int io = 0; io < 4; ++io) {
        float w0 = b_d1_w[(size_t)(i + io) * 64 + lane];
        #pragma unroll
        for (int rr = 0; rr < 4; ++rr) {
          float xv = reinterpret_cast<const float*>(&v[rr])[io];
          acc[rr] = fmaf(xv, w0, acc[rr]);
        }
      }
    }
    float s  = b_g2[lane] * rsqrtf(b_v2[lane] + EPSBN);
    float t  = b_b2[lane] - b_m2[lane] * s;
    float bs = b_d1_b[lane];
    #pragma unroll
    for (int rr = 0; rr < 4; ++rr)
      AR(rr)[lane] = tanhf(acc[rr] + bs) * s + t;
  }
  __syncthreads();
  {
    const bool m32 = (lane < 32);
    float acc[4] = {0.f, 0.f, 0.f, 0.f};
    for (int i = 0; i < 64; i += 4) {
      float4 v[4];
      #pragma unroll
      for (int rr = 0; rr < 4; ++rr) v[rr] = *reinterpret_cast<const float4*>(AR(rr) + i);
      #pragma unroll
      for (int io = 0; io < 4; ++io) {
        float w0 = m32 ? b_d2_w[(size_t)(i + io) * 32 + lane] : 0.f;
        #pragma unroll
        for (int rr = 0; rr < 4; ++rr) {
          float xv = reinterpret_cast<const float*>(&v[rr])[io];
          acc[rr] = fmaf(xv, w0, acc[rr]);
        }
      }
    }
    if (m32) {
      float bs = b_d2_b[lane];
      #pragma unroll
      for (int rr = 0; rr < 4; ++rr)
        BR(rr)[lane] = tanhf(acc[rr] + bs);
    }
  }
  __syncthreads();
  if (lane < 4) {
    int rr = lane;
    float acc = b_d3_b[0];
    #pragma unroll
    for (int i = 0; i < 32; ++i)
      acc = fmaf(BR(rr)[i], b_d3_w[i], acc);
    out[(size_t)(b0 + rr) * kOut + 120] = 1.f / (1.f + expf(-acc));
  }
  #undef AR
  #undef BR
}

extern "C" void kernel_launch(void* const* d_in, const int* in_sizes, int n_in,
                              void* d_out, int out_size, void* d_ws, size_t ws_size,
                              hipStream_t stream) {
  (void)in_sizes; (void)n_in; (void)out_size;
  const float* p[31];
  for (int i = 0; i < 31; ++i) p[i] = (const float*)d_in[i];
  float* out = (float*)d_out;

  if (ws_size >= WS_NEED && d_ws != nullptr) {
    char* ws = (char*)d_ws;
    unsigned short* W1E = (unsigned short*)(ws + OFF_W1E);
    unsigned short* W2E = (unsigned short*)(ws + OFF_W2E);
    unsigned short* W3E = (unsigned short*)(ws + OFF_W3E);
    unsigned short* W1B = (unsigned short*)(ws + OFF_W1B);
    unsigned short* W2B = (unsigned short*)(ws + OFF_W2B);
    float* BIAS         = (float*)(ws + OFF_BIAS);
    float* cwt4         = (float*)(ws + OFF_CWT);

    hipLaunchKernelGGL(prep_cwt, dim3(30), dim3(256), 0, stream, p[1], cwt4);
    hipLaunchKernelGGL(prep_pack, dim3(508), dim3(256), 0, stream,
                       p[3], p[6], p[7], p[9], p[12], p[13], p[15],
                       p[17], p[20], p[21], p[23], p[26], p[27],
                       W1E, W2E, W3E, W1B, W2B);
    hipLaunchKernelGGL(prep_bias, dim3(3), dim3(256), 0, stream,
                       p[3], p[4], p[5], p[6], p[7], p[8],
                       p[9], p[10], p[11], p[12], p[13], p[14], p[16],
                       p[17], p[18], p[19], p[20], p[21], p[22],
                       p[23], p[24], p[25], p[26], p[27], p[28],
                       p[29], p[30], BIAS);
    hipLaunchKernelGGL(fused_all, dim3(BTOT / 16), dim3(64), 0, stream,
                       p[0], cwt4, p[2], W1E, W2E, W3E, W1B, W2B, BIAS, out);
  } else {
    hipLaunchKernelGGL(fused_blink_fb, dim3(BTOT / 4), dim3(64), 0, stream,
      p[0], p[1], p[2], p[3], p[4], p[5], p[6], p[7], p[8], p[9],
      p[10], p[11], p[12], p[13], p[14], p[15], p[16], p[17], p[18], p[19],
      p[20], p[21], p[22], p[23], p[24], p[25], p[26], p[27], p[28], p[29], p[30],
      out);
  }
}

// Round 19
// 165.407 us; speedup vs baseline: 2.2533x; 2.2533x over previous
//
#include <hip/hip_runtime.h>
#include <hip/hip_bf16.h>
#include <string.h>

#define EPSBN 1e-3f

constexpr int kC1  = 192;
constexpr int kN2  = 240;
constexpr int kOut = 121;
constexpr int BTOT = 16384;

typedef __attribute__((ext_vector_type(8))) short bf16x8;
typedef __attribute__((ext_vector_type(4))) float f32x4;

__device__ __forceinline__ unsigned short f2bf(float f) {
  union { float f; unsigned u; } v; v.f = f;
  unsigned r = v.u + 0x7FFFu + ((v.u >> 16) & 1u);
  return (unsigned short)(r >> 16);
}
__device__ __forceinline__ float bf2f(unsigned short h) {
  union { unsigned u; float f; } v; v.u = ((unsigned)h) << 16;
  return v.f;
}

// ---------------- d_ws layout (bytes) ----------------
constexpr size_t OFF_W1E  = 0;
constexpr size_t OFF_W2E  = OFF_W1E + 73728;
constexpr size_t OFF_W3E  = OFF_W2E + 92160;
constexpr size_t OFF_W1B  = OFF_W3E + 65536;
constexpr size_t OFF_W2B  = OFF_W1B + 24576;
constexpr size_t OFF_BIAS = OFF_W2B + 4096;
constexpr size_t OFF_CWT  = OFF_BIAS + 2736;
constexpr size_t WS_NEED  = OFF_CWT + 122880;

// ======================= merged prep: pack + cwt + bias in ONE launch =======================
__device__ __forceinline__ void pack_one(unsigned short* dst, int idx,
                                         const float* __restrict__ W, int Ksrc, int Nsrc,
                                         int KS, const float* g, const float* v)
{
  int per_nt = KS * 512;
  int nt = idx / per_nt; int r = idx - nt * per_nt;
  int ks = r >> 9; int r2 = r & 511;
  int l = r2 >> 3; int j = r2 & 7;
  int i = ks * 32 + ((l >> 4) << 3) + j;
  int n = (nt << 4) + (l & 15);
  float val = 0.f;
  if (i < Ksrc && n < Nsrc) {
    float s = g ? g[i] * rsqrtf(v[i] + EPSBN) : 1.f;
    val = s * W[(size_t)i * Nsrc + n];
  }
  dst[idx] = f2bf(val);
}

// wave-parallel folded-bias: one 64-lane wave per output; 3 terms/lane + butterfly
__device__ __forceinline__ float wave_dot192(const float* g, const float* b,
                                             const float* m, const float* vv,
                                             const float* W, int Nsrc, int j, int lane)
{
  float p = 0.f;
  #pragma unroll
  for (int t = 0; t < 3; ++t) {
    int i = t * 64 + lane;
    float s = g[i] * rsqrtf(vv[i] + EPSBN);
    p = fmaf(b[i] - m[i] * s, W[(size_t)i * Nsrc + j], p);
  }
  #pragma unroll
  for (int o = 32; o > 0; o >>= 1) p += __shfl_xor(p, o);
  return p;
}

__global__ __launch_bounds__(256) void prep_all(
    const float* conv_w,
    const float* e_g1, const float* e_b1, const float* e_m1, const float* e_v1,
    const float* e_d1_w, const float* e_d1_b,
    const float* e_g2, const float* e_b2, const float* e_m2, const float* e_v2,
    const float* e_d2_w, const float* e_d2_b,
    const float* e_d3_w, const float* e_d3_b,
    const float* b_g1, const float* b_b1, const float* b_m1, const float* b_v1,
    const float* b_d1_w, const float* b_d1_b,
    const float* b_g2, const float* b_b2, const float* b_m2, const float* b_v2,
    const float* b_d2_w, const float* b_d2_b,
    const float* b_d3_w, const float* b_d3_b,
    unsigned short* W1E, unsigned short* W2E, unsigned short* W3E,
    unsigned short* W1B, unsigned short* W2B,
    float* BIAS, float* cwt4)
{
  const int b   = blockIdx.x;
  const int tid = threadIdx.x;

  if (b < 508) {                       // ---- pack ----
    int e = b * 256 + tid;
    if (e < 36864)               pack_one(W1E, e,          e_d1_w, 192, 192, 6, e_g1, e_v1);
    else if (e < 82944)          pack_one(W2E, e - 36864,  e_d2_w, 192, 240, 6, e_g2, e_v2);
    else if (e < 115712)         pack_one(W3E, e - 82944,  e_d3_w, 240, 120, 8, nullptr, nullptr);
    else if (e < 128000)         pack_one(W1B, e - 115712, b_d1_w, 192, 64,  6, b_g1, b_v1);
    else if (e < 130048)         pack_one(W2B, e - 128000, b_d2_w, 64,  32,  2, b_g2, b_v2);
  } else if (b < 538) {                // ---- cwt transpose ----
    int idx = (b - 508) * 256 + tid;
    if (idx < 7680) {
      int f = idx >> 6, w = idx & 63;
      float4 v;
      v.x = conv_w[(size_t)w * 360 + f * 3 + 0];
      v.y = conv_w[(size_t)w * 360 + f * 3 + 1];
      v.z = conv_w[(size_t)w * 360 + f * 3 + 2];
      v.w = 0.f;
      *reinterpret_cast<float4*>(cwt4 + (size_t)idx * 4) = v;
    }
  } else {                             // ---- bias (wave-parallel) ----
    int lane = tid & 63;
    int q = (b - 538) * 4 + (tid >> 6);
    if (q > 680) return;
    float r;
    if (q < 192) {
      r = wave_dot192(e_g1, e_b1, e_m1, e_v1, e_d1_w, 192, q, lane) + e_d1_b[q];
    } else if (q < 432) {
      int j = q - 192;
      r = wave_dot192(e_g2, e_b2, e_m2, e_v2, e_d2_w, 240, j, lane) + e_d2_b[j];
    } else if (q < 552) {
      r = e_d3_b[q - 432];
    } else if (q < 616) {
      int j = q - 552;
      r = wave_dot192(b_g1, b_b1, b_m1, b_v1, b_d1_w, 64, j, lane) + b_d1_b[j];
    } else if (q < 648) {
      int j = q - 616;
      float s = b_g2[lane] * rsqrtf(b_v2[lane] + EPSBN);
      float p = (b_b2[lane] - b_m2[lane] * s) * b_d2_w[(size_t)lane * 32 + j];
      #pragma unroll
      for (int o = 32; o > 0; o >>= 1) p += __shfl_xor(p, o);
      r = p + b_d2_b[j];
    } else if (q < 680) {
      r = b_d3_w[q - 648];
    } else {
      r = b_d3_b[0];
    }
    if (lane == 0) BIAS[q] = r;
  }
}

// ======================= FUSED (R14 exact, best known 187us) =======================
__global__ __launch_bounds__(64) void fused_all(
    const float* __restrict__ x,
    const float* __restrict__ cwt4, const float* __restrict__ conv_b,
    const unsigned short* __restrict__ W1E, const unsigned short* __restrict__ W2E,
    const unsigned short* __restrict__ W3E, const unsigned short* __restrict__ W1B,
    const unsigned short* __restrict__ W2B, const float* __restrict__ BIAS,
    float* __restrict__ out)
{
  __shared__ __align__(16) short Ac[16 * 200];     // 6.4 KB
  __shared__ __align__(16) char  ubuf[15 * 65 * 16]; // conv xt; mlp Hs/H2 alias

  float4* xt = reinterpret_cast<float4*>(ubuf);
  short*  Hs = reinterpret_cast<short*>(ubuf);
  short*  H2 = reinterpret_cast<short*>(ubuf + 6400);

  const int l = threadIdx.x;
  const int R = blockIdx.x * 16;

  // ================= conv phase =================
  {
    const float bc0 = conv_b[l * 3 + 0];
    const float bc1 = conv_b[l * 3 + 1];
    const float bc2 = conv_b[l * 3 + 2];

    for (int r = 0; r < 16; ++r) {
      const float* xrow = x + (size_t)(R + r) * 7680;
      float a0 = 0.f, a1 = 0.f, a2 = 0.f;

      for (int h = 0; h < 2; ++h) {
        #pragma unroll
        for (int i = 0; i < 15; ++i) {
          int g = i * 64 + l;
          int w = g / 15, fs = g - 15 * w;
          float4 v = *reinterpret_cast<const float4*>(xrow + w * 120 + h * 60 + 4 * fs);
          xt[fs * 65 + w] = v;
        }
        __syncthreads();

        #pragma unroll 5
        for (int fq = 0; fq < 15; ++fq) {
          float4 x4 = xt[fq * 65 + l];
          float xs[4] = {x4.x, x4.y, x4.z, x4.w};
          #pragma unroll
          for (int j = 0; j < 4; ++j) {
            int f = h * 60 + 4 * fq + j;
            float4 c4 = *reinterpret_cast<const float4*>(cwt4 + (size_t)(f * 64 + l) * 4);
            a0 = fmaf(xs[j], c4.x, a0);
            a1 = fmaf(xs[j], c4.y, a1);
            a2 = fmaf(xs[j], c4.z, a2);
          }
        }
        __syncthreads();
      }

      Ac[r * 200 + 3 * l + 0] = (short)f2bf(tanhf(a0 + bc0));
      Ac[r * 200 + 3 * l + 1] = (short)f2bf(tanhf(a1 + bc1));
      Ac[r * 200 + 3 * l + 2] = (short)f2bf(tanhf(a2 + bc2));
    }
  }
  __syncthreads();

  // ---- zero H2 k-pad [240,256) ----
  #pragma unroll
  for (int e = l; e < 256; e += 64) {
    int row = e >> 4, cc = e & 15;
    H2[row * 264 + 240 + cc] = 0;
  }

  const int arow = l & 15;
  const int kofs = (l >> 4) * 8;
  const int mb   = (l >> 4) * 4;

  // ---- d1e ----
  for (int nt = 0; nt < 12; ++nt) {
    f32x4 acc = {0.f, 0.f, 0.f, 0.f};
    const bf16x8* bp = (const bf16x8*)W1E + (size_t)(nt * 6) * 64 + l;
    #pragma unroll
    for (int ks = 0; ks < 6; ++ks) {
      bf16x8 a = *(const bf16x8*)(Ac + arow * 200 + ks * 32 + kofs);
      acc = __builtin_amdgcn_mfma_f32_16x16x32_bf16(a, bp[(size_t)ks * 64], acc, 0, 0, 0);
    }
    int n = nt * 16 + arow;
    float bv = BIAS[n];
    __syncthreads();
    #pragma unroll
    for (int r = 0; r < 4; ++r)
      Hs[(mb + r) * 200 + n] = (short)f2bf(tanhf(acc[r] + bv));
  }
  __syncthreads();

  // ---- d2e ----
  for (int nt = 0; nt < 15; ++nt) {
    f32x4 acc = {0.f, 0.f, 0.f, 0.f};
    const bf16x8* bp = (const bf16x8*)W2E + (size_t)(nt * 6) * 64 + l;
    #pragma unroll
    for (int ks = 0; ks < 6; ++ks) {
      bf16x8 a = *(const bf16x8*)(Hs + arow * 200 + ks * 32 + kofs);
      acc = __builtin_amdgcn_mfma_f32_16x16x32_bf16(a, bp[(size_t)ks * 64], acc, 0, 0, 0);
    }
    int n = nt * 16 + arow;
    float bv = BIAS[192 + n];
    #pragma unroll
    for (int r = 0; r < 4; ++r)
      H2[(mb + r) * 264 + n] = (short)f2bf(acc[r] + bv);
  }
  __syncthreads();

  // ---- d3e ----
  for (int nt = 0; nt < 8; ++nt) {
    f32x4 acc = {0.f, 0.f, 0.f, 0.f};
    const bf16x8* bp = (const bf16x8*)W3E + (size_t)(nt * 8) * 64 + l;
    #pragma unroll
    for (int ks = 0; ks < 8; ++ks) {
      bf16x8 a = *(const bf16x8*)(H2 + arow * 264 + ks * 32 + kofs);
      acc = __builtin_amdgcn_mfma_f32_16x16x32_bf16(a, bp[(size_t)ks * 64], acc, 0, 0, 0);
    }
    int n = nt * 16 + arow;
    if (n < 120) {
      float bv = BIAS[432 + n];
      #pragma unroll
      for (int r = 0; r < 4; ++r)
        out[(size_t)(R + mb + r) * kOut + n] = acc[r] + bv;
    }
  }
  __syncthreads();

  // ---- g1 blink ----
  for (int nt = 0; nt < 4; ++nt) {
    f32x4 acc = {0.f, 0.f, 0.f, 0.f};
    const bf16x8* bp = (const bf16x8*)W1B + (size_t)(nt * 6) * 64 + l;
    #pragma unroll
    for (int ks = 0; ks < 6; ++ks) {
      bf16x8 a = *(const bf16x8*)(Ac + arow * 200 + ks * 32 + kofs);
      acc = __builtin_amdgcn_mfma_f32_16x16x32_bf16(a, bp[(size_t)ks * 64], acc, 0, 0, 0);
    }
    int n = nt * 16 + arow;
    float bv = BIAS[552 + n];
    #pragma unroll
    for (int r = 0; r < 4; ++r)
      Hs[(mb + r) * 200 + n] = (short)f2bf(tanhf(acc[r] + bv));
  }
  __syncthreads();

  // ---- g2 blink ----
  for (int nt = 0; nt < 2; ++nt) {
    f32x4 acc = {0.f, 0.f, 0.f, 0.f};
    const bf16x8* bp = (const bf16x8*)W2B + (size_t)(nt * 2) * 64 + l;
    #pragma unroll
    for (int ks = 0; ks < 2; ++ks) {
      bf16x8 a = *(const bf16x8*)(Hs + arow * 200 + ks * 32 + kofs);
      acc = __builtin_amdgcn_mfma_f32_16x16x32_bf16(a, bp[(size_t)ks * 64], acc, 0, 0, 0);
    }
    int n = nt * 16 + arow;
    float bv = BIAS[616 + n];
    #pragma unroll
    for (int r = 0; r < 4; ++r)
      H2[(mb + r) * 264 + n] = (short)f2bf(tanhf(acc[r] + bv));
  }
  __syncthreads();

  // ---- out_b ----
  if (l < 16) {
    float s = BIAS[680];
    #pragma unroll
    for (int i = 0; i < 32; ++i)
      s = fmaf(bf2f((unsigned short)H2[l * 264 + i]), BIAS[648 + i], s);
    out[(size_t)(R + l) * kOut + 120] = 1.f / (1.f + expf(-s));
  }
}

// ======================= Fallback: round-5 fused kernel (known-correct, fp32) =======================
constexpr int CSTR = 193;
__global__ __launch_bounds__(64, 4) void fused_blink_fb(
    const float* __restrict__ x,
    const float* __restrict__ conv_w, const float* __restrict__ conv_b,
    const float* __restrict__ e_g1, const float* __restrict__ e_b1,
    const float* __restrict__ e_m1, const float* __restrict__ e_v1,
    const float* __restrict__ e_d1_w, const float* __restrict__ e_d1_b,
    const float* __restrict__ e_g2, const float* __restrict__ e_b2,
    const float* __restrict__ e_m2, const float* __restrict__ e_v2,
    const float* __restrict__ e_d2_w, const float* __restrict__ e_d2_b,
    const float* __restrict__ e_d3_w, const float* __restrict__ e_d3_b,
    const float* __restrict__ b_g1, const float* __restrict__ b_b1,
    const float* __restrict__ b_m1, const float* __restrict__ b_v1,
    const float* __restrict__ b_d1_w, const float* __restrict__ b_d1_b,
    const float* __restrict__ b_g2, const float* __restrict__ b_b2,
    const float* __restrict__ b_m2, const float* __restrict__ b_v2,
    const float* __restrict__ b_d2_w, const float* __restrict__ b_d2_b,
    const float* __restrict__ b_d3_w, const float* __restrict__ b_d3_b,
    float* __restrict__ out)
{
  __shared__ float comb[4 * CSTR];
  __shared__ __align__(16) float Ab[4 * kN2];
  __shared__ __align__(16) float Bb[4 * kN2];
  const int lane = threadIdx.x;
  const int b0   = blockIdx.x * 4;
  {
    const int rcv = lane >> 4, wloc = lane & 15;
    for (int wc = 0; wc < 4; ++wc) {
      const int w = wc * 16 + wloc;
      const float* xr  = x + ((size_t)(b0 + rcv) * 64 + w) * 120;
      const float* cwp = conv_w + (size_t)w * 360;
      float a0 = 0.f, a1 = 0.f, a2 = 0.f;
      for (int t = 0; t < 30; ++t) {
        float4 xv = *reinterpret_cast<const float4*>(xr + 4 * t);
        float4 c0 = *reinterpret_cast<const float4*>(cwp + 12 * t);
        float4 c1 = *reinterpret_cast<const float4*>(cwp + 12 * t + 4);
        float4 c2 = *reinterpret_cast<const float4*>(cwp + 12 * t + 8);
        a0 += xv.x * c0.x + xv.y * c0.w + xv.z * c1.z + xv.w * c2.y;
        a1 += xv.x * c0.y + xv.y * c1.x + xv.z * c1.w + xv.w * c2.z;
        a2 += xv.x * c0.z + xv.y * c1.y + xv.z * c2.x + xv.w * c2.w;
      }
      comb[rcv * CSTR + 3 * w + 0] = tanhf(a0 + conv_b[3 * w + 0]);
      comb[rcv * CSTR + 3 * w + 1] = tanhf(a1 + conv_b[3 * w + 1]);
      comb[rcv * CSTR + 3 * w + 2] = tanhf(a2 + conv_b[3 * w + 2]);
    }
  }
  __syncthreads();
  #define AR(rr) (Ab + (size_t)(rr) * kN2)
  #define BR(rr) (Bb + (size_t)(rr) * kN2)
  #pragma unroll
  for (int q = 0; q < 12; ++q) {
    int rr = q / 3, cc = q % 3;
    int i = cc * 64 + lane;
    float s = e_g1[i] * rsqrtf(e_v1[i] + EPSBN);
    AR(rr)[i] = comb[rr * CSTR + i] * s + (e_b1[i] - e_m1[i] * s);
  }
  __syncthreads();
  {
    float acc[4][3];
    #pragma unroll
    for (int rr = 0; rr < 4; ++rr) { acc[rr][0]=acc[rr][1]=acc[rr][2]=0.f; }
    for (int i = 0; i < kC1; i += 4) {
      float4 v[4];
      #pragma unroll
      for (int rr = 0; rr < 4; ++rr) v[rr] = *reinterpret_cast<const float4*>(AR(rr) + i);
      #pragma unroll
      for (int io = 0; io < 4; ++io) {
        const float* wp = e_d1_w + (size_t)(i + io) * kC1 + lane;
        float w0 = wp[0], w1 = wp[64], w2 = wp[128];
        #pragma unroll
        for (int rr = 0; rr < 4; ++rr) {
          float xv = reinterpret_cast<const float*>(&v[rr])[io];
          acc[rr][0] = fmaf(xv, w0, acc[rr][0]);
          acc[rr][1] = fmaf(xv, w1, acc[rr][1]);
          acc[rr][2] = fmaf(xv, w2, acc[rr][2]);
        }
      }
    }
    #pragma unroll
    for (int c = 0; c < 3; ++c) {
      int j = c * 64 + lane;
      float s  = e_g2[j] * rsqrtf(e_v2[j] + EPSBN);
      float t  = e_b2[j] - e_m2[j] * s;
      float bs = e_d1_b[j];
      #pragma unroll
      for (int rr = 0; rr < 4; ++rr)
        BR(rr)[j] = tanhf(acc[rr][c] + bs) * s + t;
    }
  }
  __syncthreads();
  {
    const bool m3 = (lane < 48);
    float acc[4][4];
    #pragma unroll
    for (int rr = 0; rr < 4; ++rr) { acc[rr][0]=acc[rr][1]=acc[rr][2]=acc[rr][3]=0.f; }
    for (int i = 0; i < kC1; i += 4) {
      float4 v[4];
      #pragma unroll
      for (int rr = 0; rr < 4; ++rr) v[rr] = *reinterpret_cast<const float4*>(BR(rr) + i);
      #pragma unroll
      for (int io = 0; io < 4; ++io) {
        const float* wp = e_d2_w + (size_t)(i + io) * kN2 + lane;
        float w0 = wp[0], w1 = wp[64], w2 = wp[128];
        float w3 = m3 ? wp[192] : 0.f;
        #pragma unroll
        for (int rr = 0; rr < 4; ++rr) {
          float xv = reinterpret_cast<const float*>(&v[rr])[io];
          acc[rr][0] = fmaf(xv, w0, acc[rr][0]);
          acc[rr][1] = fmaf(xv, w1, acc[rr][1]);
          acc[rr][2] = fmaf(xv, w2, acc[rr][2]);
          acc[rr][3] = fmaf(xv, w3, acc[rr][3]);
        }
      }
    }
    #pragma unroll
    for (int c = 0; c < 4; ++c) {
      int j = c * 64 + lane;
      if (c < 3 || m3) {
        float bs = e_d2_b[j];
        #pragma unroll
        for (int rr = 0; rr < 4; ++rr)
          AR(rr)[j] = acc[rr][c] + bs;
      }
    }
  }
  __syncthreads();
  #pragma unroll
  for (int q = 0; q < 12; ++q) {
    int rr = q / 3, cc = q % 3;
    int i = cc * 64 + lane;
    float s = b_g1[i] * rsqrtf(b_v1[i] + EPSBN);
    BR(rr)[i] = comb[rr * CSTR + i] * s + (b_b1[i] - b_m1[i] * s);
  }
  {
    const bool m56 = (lane < 56);
    float acc[4][2];
    #pragma unroll
    for (int rr = 0; rr < 4; ++rr) { acc[rr][0]=acc[rr][1]=0.f; }
    for (int i = 0; i < kN2; i += 4) {
      float4 v[4];
      #pragma unroll
      for (int rr = 0; rr < 4; ++rr) v[rr] = *reinterpret_cast<const float4*>(AR(rr) + i);
      #pragma unroll
      for (int io = 0; io < 4; ++io) {
        const float* wp = e_d3_w + (size_t)(i + io) * 120 + lane;
        float w0 = wp[0];
        float w1 = m56 ? wp[64] : 0.f;
        #pragma unroll
        for (int rr = 0; rr < 4; ++rr) {
          float xv = reinterpret_cast<const float*>(&v[rr])[io];
          acc[rr][0] = fmaf(xv, w0, acc[rr][0]);
          acc[rr][1] = fmaf(xv, w1, acc[rr][1]);
        }
      }
    }
    #pragma unroll
    for (int c = 0; c < 2; ++c) {
      int j = c * 64 + lane;
      if (j < 120) {
        float bs = e_d3_b[j];
        #pragma unroll
        for (int rr = 0; rr < 4; ++rr)
          out[(size_t)(b0 + rr) * kOut + j] = acc[rr][c] + bs;
      }
    }
  }
  __syncthreads();
  {
    float acc[4] = {0.f, 0.f, 0.f, 0.f};
    for (int i = 0; i < kC1; i += 4) {
      float4 v[4];
      #pragma unroll
      for (int rr = 0; rr < 4; ++rr) v[rr] = *reinterpret_cast<const float4*>(BR(rr) + i);
      #pragma unroll
      for (int io = 0; io < 4; ++io) {
        float w0 = b_d1_w[(size_t)(i + io) * 64 + lane];
        #pragma unroll
        for (int rr = 0; rr < 4; ++rr) {
          float xv = reinterpret_cast<const float*>(&v[rr])[io];
          acc[rr] = fmaf(xv, w0, acc[rr]);
        }
      }
    }
    float s  = b_g2[lane] * rsqrtf(b_v2[lane] + EPSBN);
    float t  = b_b2[lane] - b_m2[lane] * s;
    float bs = b_d1_b[lane];
    #pragma unroll
    for (int rr = 0; rr < 4; ++rr)
      AR(rr)[lane] = tanhf(acc[rr] + bs) * s + t;
  }
  __syncthreads();
  {
    const bool m32 = (lane < 32);
    float acc[4] = {0.f, 0.f, 0.f, 0.f};
    for (int i = 0; i < 64; i += 4) {
      float4 v[4];
      #pragma unroll
      for (int rr = 0; rr < 4; ++rr) v[rr] = *reinterpret_cast<const float4*>(AR(rr) + i);
      #pragma unroll
      for (int io = 0; io < 4; ++io) {
        float w0 = m32 ? b_d2_w[(size_t)(i + io) * 32 + lane] : 0.f;
        #pragma unroll
        for (int rr = 0; rr < 4; ++rr) {
          float xv = reinterpret_cast<const float*>(&v[rr])[io];
          acc[rr] = fmaf(xv, w0, acc[rr]);
        }
      }
    }
    if (m32) {
      float bs = b_d2_b[lane];
      #pragma unroll
      for (int rr = 0; rr < 4; ++rr)
        BR(rr)[lane] = tanhf(acc[rr] + bs);
    }
  }
  __syncthreads();
  if (lane < 4) {
    int rr = lane;
    float acc = b_d3_b[0];
    #pragma unroll
    for (int i = 0; i < 32; ++i)
      acc = fmaf(BR(rr)[i], b_d3_w[i], acc);
    out[(size_t)(b0 + rr) * kOut + 120] = 1.f / (1.f + expf(-acc));
  }
  #undef AR
  #undef BR
}

extern "C" void kernel_launch(void* const* d_in, const int* in_sizes, int n_in,
                              void* d_out, int out_size, void* d_ws, size_t ws_size,
                              hipStream_t stream) {
  (void)in_sizes; (void)n_in; (void)out_size;
  const float* p[31];
  for (int i = 0; i < 31; ++i) p[i] = (const float*)d_in[i];
  float* out = (float*)d_out;

  if (ws_size >= WS_NEED && d_ws != nullptr) {
    char* ws = (char*)d_ws;
    unsigned short* W1E = (unsigned short*)(ws + OFF_W1E);
    unsigned short* W2E = (unsigned short*)(ws + OFF_W2E);
    unsigned short* W3E = (unsigned short*)(ws + OFF_W3E);
    unsigned short* W1B = (unsigned short*)(ws + OFF_W1B);
    unsigned short* W2B = (unsigned short*)(ws + OFF_W2B);
    float* BIAS         = (float*)(ws + OFF_BIAS);
    float* cwt4         = (float*)(ws + OFF_CWT);

    // merged prep: pack(508) + cwt(30) + bias(171 blocks x 4 wave-outputs)
    hipLaunchKernelGGL(prep_all, dim3(709), dim3(256), 0, stream,
                       p[1],
                       p[3], p[4], p[5], p[6], p[7], p[8],
                       p[9], p[10], p[11], p[12], p[13], p[14],
                       p[15], p[16],
                       p[17], p[18], p[19], p[20], p[21], p[22],
                       p[23], p[24], p[25], p[26], p[27], p[28],
                       p[29], p[30],
                       W1E, W2E, W3E, W1B, W2B, BIAS, cwt4);
    hipLaunchKernelGGL(fused_all, dim3(BTOT / 16), dim3(64), 0, stream,
                       p[0], cwt4, p[2], W1E, W2E, W3E, W1B, W2B, BIAS, out);
  } else {
    hipLaunchKernelGGL(fused_blink_fb, dim3(BTOT / 4), dim3(64), 0, stream,
      p[0], p[1], p[2], p[3], p[4], p[5], p[6], p[7], p[8], p[9],
      p[10], p[11], p[12], p[13], p[14], p[15], p[16], p[17], p[18], p[19],
      p[20], p[21], p[22], p[23], p[24], p[25], p[26], p[27], p[28], p[29], p[30],
      out);
  }
}